// Round 12
// baseline (173.640 us; speedup 1.0000x reference)
//
#include <hip/hip_runtime.h>

// LSTM text classifier: emb-gather -> LSTM(512 steps) -> FC(32->2)
//   R12 = R11 with the type fix (__fp16 vector for cvt_pkrtz/fdot2 builtins).
//   Pair-packed f16 dot2 engine. R6/R9/R10 all converge at ~423 busy
//   cyc/step (three different h-fanout engines) -> cut instruction COUNT:
//   - lane (m=l&15, q=l>>4) owns gate-type q for cells 2m,2m+1
//   - h packed f16x2 {h_2m,h_2m+1} per lane (cvt_pkrtz, periodic-16) ->
//     15 wave-ROR DPPs walk all 16 pairs; 32 v_dot2_f32_f16 do 64 products
//   - gate exchange: permlane16_swap + 2x permlane32_swap per cell value
//     (perm32 .x/.y verified since R8; perm16 order runtime-probed)
//   - input-proj stays f32 (ptab); c,gates f32; only h,w_hh are f16 (dot2)
//   amdgpu_waves_per_eu(1,1) kept (R6: weights register-resident).

#define LOG2E 1.44269504088896340736f

typedef float f32x2 __attribute__((ext_vector_type(2)));
typedef unsigned uv2 __attribute__((ext_vector_type(2)));
typedef float f32x32 __attribute__((ext_vector_type(32)));
typedef __fp16 h16x2 __attribute__((ext_vector_type(2)));  // builtin-compatible

__device__ __forceinline__ float fast_rcp(float x) { return __builtin_amdgcn_rcpf(x); }
__device__ __forceinline__ float fast_exp2(float x) { return __builtin_amdgcn_exp2f(x); }

__device__ __forceinline__ h16x2 cvtpk(float a, float b) {
#if __has_builtin(__builtin_amdgcn_cvt_pkrtz)
    return __builtin_amdgcn_cvt_pkrtz(a, b);
#else
    h16x2 r; r.x = (__fp16)a; r.y = (__fp16)b; return r;
#endif
}

#if __has_builtin(__builtin_amdgcn_fdot2)
#define FDOT2(A, B, C) __builtin_amdgcn_fdot2((A), (B), (C), false)
#else
__device__ __forceinline__ float fdot2_emu(h16x2 a, h16x2 b, float c) {
    return fmaf((float)a.x, (float)b.x, fmaf((float)a.y, (float)b.y, c));
}
#define FDOT2(A, B, C) fdot2_emu((A), (B), (C))
#endif

// wave rotate-by-1 (verified R10, absmax 0 with runtime dir probe)
__device__ __forceinline__ unsigned rot1u(unsigned v) {
    return (unsigned)__builtin_amdgcn_mov_dpp((int)v, 0x13C, 0xF, 0xF, true);
}

// 16-block swap, dual outputs; ordering resolved by runtime probe (ok16)
__device__ __forceinline__ uv2 p16swap(unsigned x) {
#if __has_builtin(__builtin_amdgcn_permlane16_swap)
    return __builtin_amdgcn_permlane16_swap(x, x, false, false);
#else
    unsigned other = (unsigned)__shfl_xor((int)x, 16, 64);
    uv2 r;
    if (threadIdx.x & 16) { r.x = other; r.y = x; }
    else                  { r.x = x;     r.y = other; }
    return r;
#endif
}

// ---------------- K1: projected + prescaled embedding table ----------------
// Layout: lane (m,q) -> float2 { proj[q*32+2m], proj[q*32+2m+1] } * s_q
__global__ __launch_bounds__(64, 1) void build_ptab(
    const float4* __restrict__ emb4, const float4* __restrict__ wih4,
    const float* __restrict__ bih, const float* __restrict__ bhh,
    float2* __restrict__ ptab, int nrows) {
    const int lane = threadIdx.x;
    const int m = lane & 15, q = lane >> 4;
    const int r0 = q * 32 + 2 * m, r1 = r0 + 1;
    const float sq = (q == 2) ? (2.0f * LOG2E) : (-LOG2E);

    float w0[32], w1[32];
#pragma unroll
    for (int t = 0; t < 8; ++t) {
        float4 a = wih4[r0 * 8 + t];
        float4 b = wih4[r1 * 8 + t];
        w0[4 * t + 0] = a.x; w0[4 * t + 1] = a.y; w0[4 * t + 2] = a.z; w0[4 * t + 3] = a.w;
        w1[4 * t + 0] = b.x; w1[4 * t + 1] = b.y; w1[4 * t + 2] = b.z; w1[4 * t + 3] = b.w;
    }
    const float bias0 = bih[r0] + bhh[r0];
    const float bias1 = bih[r1] + bhh[r1];

    for (int v = blockIdx.x; v < nrows; v += gridDim.x) {
        float a0 = bias0, a1 = bias1;
#pragma unroll
        for (int t = 0; t < 8; ++t) {
            float4 e = emb4[v * 8 + t];  // wave-uniform -> cache broadcast
            a0 = fmaf(e.x, w0[4 * t + 0], a0);
            a0 = fmaf(e.y, w0[4 * t + 1], a0);
            a0 = fmaf(e.z, w0[4 * t + 2], a0);
            a0 = fmaf(e.w, w0[4 * t + 3], a0);
            a1 = fmaf(e.x, w1[4 * t + 0], a1);
            a1 = fmaf(e.y, w1[4 * t + 1], a1);
            a1 = fmaf(e.z, w1[4 * t + 2], a1);
            a1 = fmaf(e.w, w1[4 * t + 3], a1);
        }
        ptab[v * 64 + lane] = make_float2(a0 * sq, a1 * sq);  // coalesced 512B/row
    }
}

#define REP16(M) M(0) M(1) M(2) M(3) M(4) M(5) M(6) M(7) M(8) M(9) M(10) M(11) \
    M(12) M(13) M(14) M(15)

// f16 weight pairs for the P-chain: slot J pairs with P after J rotations
#define WDECL(J) h16x2 wL##J, wH##J;
#define WLOAD(J)                                                               \
    {                                                                          \
        int _pi = (m - dir * (J)) & 15;                                        \
        int _c0 = 2 * _pi;                                                     \
        wL##J = cvtpk(whh[r0w + _c0] * sq, whh[r0w + _c0 + 1] * sq);           \
        wH##J = cvtpk(whh[r1w + _c0] * sq, whh[r1w + _c0 + 1] * sq);           \
    }

// one dot slot: dot2 both rows with current P, then advance P
#define DOTP(J, AL, AH)                                                        \
    {                                                                          \
        h16x2 _ph = __builtin_bit_cast(h16x2, _Pu);                            \
        AL = FDOT2(wL##J, _ph, AL);                                            \
        AH = FDOT2(wH##J, _ph, AH);                                            \
        _Pu = rot1u(_Pu);                                                      \
    }
#define DOTP_LAST(J, AL, AH)                                                   \
    {                                                                          \
        h16x2 _ph = __builtin_bit_cast(h16x2, _Pu);                            \
        AL = FDOT2(wL##J, _ph, AL);                                            \
        AH = FDOT2(wH##J, _ph, AH);                                            \
    }

// deliver one cell-value's 4 gate types to all lanes:
// p16swap splits even/odd 16-blocks (probe ok16), perm32 broadcasts halves.
// lo-half holds types {0,1}=(i,f), hi-half {2,3}=(g,o).
#define EX4(V, I_, F_, G_, O_)                                                 \
    {                                                                          \
        uv2 _t = p16swap(__float_as_uint(V));                                  \
        unsigned _Eu = ok16 ? _t.x : _t.y; /* even block: i (lo) / g (hi) */   \
        unsigned _Ou = ok16 ? _t.y : _t.x; /* odd  block: f (lo) / o (hi) */   \
        uv2 _s = __builtin_amdgcn_permlane32_swap(_Eu, _Eu, false, false);     \
        uv2 _u = __builtin_amdgcn_permlane32_swap(_Ou, _Ou, false, false);     \
        I_ = __uint_as_float(_s.x); G_ = __uint_as_float(_s.y);                \
        F_ = __uint_as_float(_u.x); O_ = __uint_as_float(_u.y);                \
    }

// one LSTM step; P = f32x2 {proj for cell-2m row, cell-2m+1 row} (prescaled).
// State: Ppack (f16x2 {h_2m,h_2m+1}), h_lo,h_hi (f32), cs_lo,cs_hi (f32).
#define STEP(P)                                                                \
    do {                                                                       \
        float _aL0 = (P).x, _aL1 = 0.0f, _aH0 = (P).y, _aH1 = 0.0f;            \
        unsigned _Pu = __builtin_bit_cast(unsigned, Ppack);                    \
        DOTP(0, _aL0, _aH0) DOTP(1, _aL1, _aH1)                                \
        DOTP(2, _aL0, _aH0) DOTP(3, _aL1, _aH1)                                \
        DOTP(4, _aL0, _aH0) DOTP(5, _aL1, _aH1)                                \
        DOTP(6, _aL0, _aH0) DOTP(7, _aL1, _aH1)                                \
        DOTP(8, _aL0, _aH0) DOTP(9, _aL1, _aH1)                                \
        DOTP(10, _aL0, _aH0) DOTP(11, _aL1, _aH1)                              \
        DOTP(12, _aL0, _aH0) DOTP(13, _aL1, _aH1)                              \
        DOTP(14, _aL0, _aH0) DOTP_LAST(15, _aL1, _aH1)                         \
        float _AL = _aL0 + _aL1; /* preact*s_q, cell 2m  (my type q) */        \
        float _AH = _aH0 + _aH1; /* preact*s_q, cell 2m+1            */        \
        float _RL = fast_rcp(1.0f + fast_exp2(_AL));                           \
        float _RH = fast_rcp(1.0f + fast_exp2(_AH));                           \
        float _vL = fmaf(kq, _RL, bq); /* sigmoid or tanh per type */          \
        float _vH = fmaf(kq, _RH, bq);                                         \
        float _iL, _fL, _gL, _oL, _iH, _fH, _gH, _oH;                          \
        EX4(_vL, _iL, _fL, _gL, _oL)                                           \
        EX4(_vH, _iH, _fH, _gH, _oH)                                           \
        cs_lo = fmaf(_fL, cs_lo, _iL * _gL);                                   \
        cs_hi = fmaf(_fH, cs_hi, _iH * _gH);                                   \
        float _TL = fmaf(-2.0f, fast_rcp(1.0f + fast_exp2(cs_lo * (2.0f * LOG2E))), 1.0f); \
        float _TH = fmaf(-2.0f, fast_rcp(1.0f + fast_exp2(cs_hi * (2.0f * LOG2E))), 1.0f); \
        h_lo = _oL * _TL;                                                      \
        h_hi = _oH * _TH;                                                      \
        Ppack = cvtpk(h_lo, h_hi);                                             \
    } while (0)

// ---------------- K2: LSTM scan, one wave per batch element ----------------
template <bool PTAB>
__global__ __launch_bounds__(64)
__attribute__((amdgpu_waves_per_eu(1, 1)))  // pressure target = 1 wave/EU (R6, verified)
void lstm_scan(
    const int* __restrict__ x,
    const float2* __restrict__ ptab,
    const float* __restrict__ emb,
    const float* __restrict__ wih,
    const float* __restrict__ bih,
    const float* __restrict__ bhh,
    const float* __restrict__ whh,
    const float* __restrict__ fcw,
    const float* __restrict__ fcb,
    float* __restrict__ out,
    int S) {
    extern __shared__ int xrow[];
    const int b = blockIdx.x;
    const int lane = threadIdx.x;
    const int m = lane & 15, q = lane >> 4;
    const int r0 = q * 32 + 2 * m, r1 = r0 + 1;
    const int r0w = r0 * 32, r1w = r1 * 32;
    const float sq = (q == 2) ? (2.0f * LOG2E) : (-LOG2E);
    const float kq = (q == 2) ? -2.0f : 1.0f;  // v = kq*R + bq: sigmoid=R, tanh=1-2R
    const float bq = (q == 2) ? 1.0f : 0.0f;

    // token ids in LDS, padded so the prefetch ring never reads OOB
    for (int i = lane; i < S + 16; i += 64) xrow[i] = (i < S) ? x[(size_t)b * S + i] : 0;
    __syncthreads();

    // probe wave-ROR direction (verified pattern, R10)
    int dir;
    {
        int g = __builtin_amdgcn_mov_dpp(lane, 0x13C, 0xF, 0xF, true);
        dir = (g == ((lane + 63) & 63)) ? 1 : -1;  // received from lane-1 -> pair idx (m-j)
    }
    // probe p16swap output ordering (binary ambiguity -> cndmask in EX4)
    bool ok16;
    {
        uv2 t = p16swap((unsigned)lane);
        ok16 = (t.x == (unsigned)(lane & ~16));
    }

    REP16(WDECL)
    REP16(WLOAD)

    float h_lo = 0.0f, h_hi = 0.0f, cs_lo = 0.0f, cs_hi = 0.0f;
    h16x2 Ppack = cvtpk(0.0f, 0.0f);

    if constexpr (PTAB) {
        const char* pb = (const char*)ptab + (unsigned)(lane << 3);
        int i0 = xrow[4], i1 = xrow[5], i2 = xrow[6], i3 = xrow[7];
        f32x2 p0 = *(const f32x2*)(pb + ((unsigned)xrow[0] << 9));
        f32x2 p1 = *(const f32x2*)(pb + ((unsigned)xrow[1] << 9));
        f32x2 p2 = *(const f32x2*)(pb + ((unsigned)xrow[2] << 9));
        f32x2 p3 = *(const f32x2*)(pb + ((unsigned)xrow[3] << 9));
        int t = 0;
        for (; t + 8 <= S; t += 4) {
            STEP(p0); p0 = *(const f32x2*)(pb + ((unsigned)i0 << 9)); i0 = xrow[t + 8];
            STEP(p1); p1 = *(const f32x2*)(pb + ((unsigned)i1 << 9)); i1 = xrow[t + 9];
            STEP(p2); p2 = *(const f32x2*)(pb + ((unsigned)i2 << 9)); i2 = xrow[t + 10];
            STEP(p3); p3 = *(const f32x2*)(pb + ((unsigned)i3 << 9)); i3 = xrow[t + 11];
        }
        if (t + 0 < S) STEP(p0);
        if (t + 1 < S) STEP(p1);
        if (t + 2 < S) STEP(p2);
        if (t + 3 < S) STEP(p3);
        if (t + 4 < S) { f32x2 qq = *(const f32x2*)(pb + ((unsigned)i0 << 9)); STEP(qq); }
        if (t + 5 < S) { f32x2 qq = *(const f32x2*)(pb + ((unsigned)i1 << 9)); STEP(qq); }
        if (t + 6 < S) { f32x2 qq = *(const f32x2*)(pb + ((unsigned)i2 << 9)); STEP(qq); }
    } else {
        // fallback: on-the-fly input projection, same (m,q) layout; cold path
        f32x32 wi0, wi1;
        {
            const float4* wih4 = (const float4*)wih;
#pragma unroll
            for (int t = 0; t < 8; ++t) {
                float4 a = wih4[r0 * 8 + t];
                float4 bb = wih4[r1 * 8 + t];
                wi0[4 * t + 0] = a.x * sq; wi0[4 * t + 1] = a.y * sq;
                wi0[4 * t + 2] = a.z * sq; wi0[4 * t + 3] = a.w * sq;
                wi1[4 * t + 0] = bb.x * sq; wi1[4 * t + 1] = bb.y * sq;
                wi1[4 * t + 2] = bb.z * sq; wi1[4 * t + 3] = bb.w * sq;
            }
        }
        const float bias0 = (bih[r0] + bhh[r0]) * sq;
        const float bias1 = (bih[r1] + bhh[r1]) * sq;
        const float4* emb4 = (const float4*)emb;
        for (int t = 0; t < S; ++t) {
            int idx = xrow[t];
            float a0 = bias0, a1 = bias1;
#pragma unroll
            for (int u = 0; u < 8; ++u) {
                float4 e = emb4[(size_t)idx * 8 + u];
                a0 = fmaf(e.x, wi0[4 * u + 0], a0);
                a0 = fmaf(e.y, wi0[4 * u + 1], a0);
                a0 = fmaf(e.z, wi0[4 * u + 2], a0);
                a0 = fmaf(e.w, wi0[4 * u + 3], a0);
                a1 = fmaf(e.x, wi1[4 * u + 0], a1);
                a1 = fmaf(e.y, wi1[4 * u + 1], a1);
                a1 = fmaf(e.z, wi1[4 * u + 2], a1);
                a1 = fmaf(e.w, wi1[4 * u + 3], a1);
            }
            f32x2 _p; _p.x = a0; _p.y = a1;
            STEP(_p);
        }
    }

    // FC: lane holds h for cells 2m, 2m+1; use lanes 0..15 only (4x duplicate)
    float w0a = fcw[2 * m], w0b = fcw[2 * m + 1];
    float w1a = fcw[32 + 2 * m], w1b = fcw[33 + 2 * m];
    float p0v = (lane < 16) ? fmaf(h_lo, w0a, h_hi * w0b) : 0.0f;
    float p1v = (lane < 16) ? fmaf(h_lo, w1a, h_hi * w1b) : 0.0f;
#pragma unroll
    for (int mm = 32; mm >= 1; mm >>= 1) {
        p0v += __shfl_xor(p0v, mm, 64);
        p1v += __shfl_xor(p1v, mm, 64);
    }
    if (lane == 0) {
        out[b * 2 + 0] = p0v + fcb[0];
        out[b * 2 + 1] = p1v + fcb[1];
    }
}

extern "C" void kernel_launch(void* const* d_in, const int* in_sizes, int n_in,
                              void* d_out, int out_size, void* d_ws, size_t ws_size,
                              hipStream_t stream) {
    const int* x = (const int*)d_in[0];
    const float* emb = (const float*)d_in[1];
    const float* wih = (const float*)d_in[2];
    const float* whh = (const float*)d_in[3];
    const float* bih = (const float*)d_in[4];
    const float* bhh = (const float*)d_in[5];
    const float* fcw = (const float*)d_in[6];
    const float* fcb = (const float*)d_in[7];
    float* out = (float*)d_out;

    const int B = out_size / 2;          // 1024
    const int S = in_sizes[0] / B;       // 512
    const int nrows = in_sizes[1] / 32;  // 50001 (EMB=32)

    const size_t need = (size_t)nrows * 64 * sizeof(float2);  // 25.6 MB
    const size_t smem = (size_t)(S + 16) * sizeof(int);

    if (ws_size >= need) {
        float2* ptab = (float2*)d_ws;
        int nb = nrows < 8192 ? nrows : 8192;
        build_ptab<<<nb, 64, 0, stream>>>((const float4*)emb, (const float4*)wih,
                                          bih, bhh, ptab, nrows);
        lstm_scan<true><<<B, 64, smem, stream>>>(x, ptab, emb, wih, bih, bhh, whh,
                                                 fcw, fcb, out, S);
    } else {
        lstm_scan<false><<<B, 64, smem, stream>>>(x, nullptr, emb, wih, bih, bhh, whh,
                                                  fcw, fcb, out, S);
    }
}